// Round 11
// baseline (5279.935 us; speedup 1.0000x reference)
//
#include <hip/hip_runtime.h>
#include <cstdint>
#include <cmath>

#define S_LEN 1024
#define BATCH 64
#define IN_SZ 256
#define HID 512
#define OUT_SZ 256
#define WIH_LD 768  // W_ih leading dim = IN_SZ + HID
#define BH (BATCH * HID)            // 32768
#define XP_FLOATS (S_LEN * BH)      // 33,554,432 floats (128 MB)

// ws word layout after xp (wbase = ws + XP_FLOATS):
//  [0, 131072)         whB   (Wh B-fragments, 32768 uint4 = 512 KB; dead after rnn)
//  [131072, 196608)    wpk   (xproj B-fragments, 16384 uint4 = 256 KB)
//  overlays (used only after rnn completes):
//  [0, 65536)          sc_g[64][1024]
//  [65536, 98304)      ctx_g[64][512]

typedef _Float16 f16x8 __attribute__((ext_vector_type(8)));
typedef float f32x4 __attribute__((ext_vector_type(4)));

// Pack Wh (W_ih[:, 256:768]) into MFMA B-fragment layout, f16.
// whB[(nt*16 + kt)*64 + lane] = 8 f16: B[k = kt*32 + (lane>>4)*8 + i][n = nt*16 + (lane&15)]
// where B[k][n] = Wh[n][k] = W_ih[n][256+k].  (same verified layout as pack_wf16)
__global__ __launch_bounds__(256) void pack_whB(const float* __restrict__ W_ih,
                                                uint4* __restrict__ whB) {
    int idx  = blockIdx.x * 256 + threadIdx.x;   // 0..32767
    int lane = idx & 63;
    int kt   = (idx >> 6) & 15;
    int nt   = idx >> 10;                        // 0..31
    int n = nt * 16 + (lane & 15);
    int k = kt * 32 + ((lane >> 4) << 3);
    const float* src = W_ih + (size_t)n * WIH_LD + IN_SZ + k;
    union { uint4 u; _Float16 h[8]; } v;
#pragma unroll
    for (int i = 0; i < 8; ++i) v.h[i] = (_Float16)src[i];
    whB[idx] = v.u;
}

// Pack Wx (W_ih[:, 0:256]) into MFMA B-fragment layout, f16.
__global__ __launch_bounds__(256) void pack_wf16(const float* __restrict__ W_ih,
                                                 uint4* __restrict__ wpk) {
    int idx = blockIdx.x * 256 + threadIdx.x;   // 0..16383
    if (idx >= 16384) return;
    int nt   = idx >> 9;
    int ks   = (idx >> 6) & 7;
    int lane = idx & 63;
    int n  = nt * 16 + (lane & 15);
    int kb = ks * 32 + (lane >> 4) * 8;
    const float* src = W_ih + (size_t)n * WIH_LD + kb;
    union { uint4 u; _Float16 h[8]; } v;
#pragma unroll
    for (int i = 0; i < 8; ++i) v.h[i] = (_Float16)src[i];
    wpk[idx] = v.u;
}

// xp[s][b][h] = dot(x[b][s][:], Wx[h][:]) + b_ih[h], via f16 MFMA (fp32 accum).
#define AH_LD 264   // 256 + 8-half pad
__global__ __launch_bounds__(256) void xproj_mfma(const float* __restrict__ x,
                                                  const uint4* __restrict__ wpk,
                                                  const float* __restrict__ b_ih,
                                                  float* __restrict__ xp) {
    const int s    = blockIdx.x;
    const int half = blockIdx.y;
    const int tid  = threadIdx.x;
    __shared__ __align__(16) _Float16 Ah[32 * AH_LD];
    __shared__ float bsh[HID];
    bsh[tid] = b_ih[tid];
    bsh[tid + 256] = b_ih[tid + 256];
    {
        int r  = tid >> 3;
        int c0 = (tid & 7) * 32;
        const float4* s4 = (const float4*)(x + ((size_t)(half * 32 + r) * S_LEN + s) * IN_SZ + c0);
        _Float16* dst = &Ah[r * AH_LD + c0];
#pragma unroll
        for (int i = 0; i < 8; ++i) {
            float4 v = s4[i];
            dst[4 * i + 0] = (_Float16)v.x;
            dst[4 * i + 1] = (_Float16)v.y;
            dst[4 * i + 2] = (_Float16)v.z;
            dst[4 * i + 3] = (_Float16)v.w;
        }
    }
    __syncthreads();
    const int lane = tid & 63;
    const int w    = tid >> 6;
    const int mt   = w & 1;
    const int ntb  = (w >> 1) * 16;
    f16x8 areg[8];
#pragma unroll
    for (int ks = 0; ks < 8; ++ks)
        areg[ks] = *(const f16x8*)&Ah[(mt * 16 + (lane & 15)) * AH_LD + ks * 32 + (lane >> 4) * 8];
    const int brow  = half * 32 + mt * 16 + (lane >> 4) * 4;
    const int ncol0 = lane & 15;
    for (int nt2 = 0; nt2 < 16; ++nt2) {
        int nt = ntb + nt2;
        const uint4* bp = wpk + (size_t)nt * 8 * 64 + lane;
        f32x4 acc = {0.f, 0.f, 0.f, 0.f};
#pragma unroll
        for (int ks = 0; ks < 8; ++ks) {
            uint4 bu = bp[ks * 64];
            acc = __builtin_amdgcn_mfma_f32_16x16x32_f16(
                areg[ks], __builtin_bit_cast(f16x8, bu), acc, 0, 0, 0);
        }
        int n = nt * 16 + ncol0;
        float bias = bsh[n];
        float* outp = xp + (size_t)s * BH + (size_t)brow * HID + n;
#pragma unroll
        for (int r = 0; r < 4; ++r) outp[(size_t)r * HID] = acc[r] + bias;
    }
}

// Recurrence via MFMA: 4 WGs, each WG = 16 batches (one M-tile), 256 thr
// (4 waves, 1 wave/SIMD -> 512-reg cap; B-frags live in VGPR/AGPR, MFMA reads
// AGPR natively). Wave w owns n in [w*128, (w+1)*128) = 8 n-tiles.
// Per wave per step: 16 kt x 8 ntl = 128 MFMA. B tiers: kt 0..11 registers,
// kt 12..14 LDS, kt 15 streamed (L1-resident, loop-invariant address).
// h state: f16 in LDS, A-fragment-readable raw layout, double-buffered,
// row stride 520 halves (16B-aligned b128 reads, 2-way banks = free).
__global__ __launch_bounds__(256, 1) void rnn_mfma(const uint4* __restrict__ whB,
                                                   float* __restrict__ xp) {
    const int g    = blockIdx.x;        // batches g*16 .. g*16+15
    const int tid  = threadIdx.x;
    const int lane = tid & 63;
    const int w    = tid >> 6;          // wave 0..3

    __shared__ uint4 Blds[4 * 8 * 3 * 64];              // 96 KB: kt 12..14
    __shared__ __align__(16) _Float16 hA[2][16][520];   // 32.5 KB

    const uint4* bw = whB + (size_t)w * 8192 + lane;

    f16x8 Breg[96];                     // kt 0..11 x ntl 0..7
#pragma unroll
    for (int ntl = 0; ntl < 8; ++ntl)
#pragma unroll
        for (int kt = 0; kt < 12; ++kt)
            Breg[ntl * 12 + kt] = __builtin_bit_cast(f16x8, bw[(ntl * 16 + kt) * 64]);

#pragma unroll
    for (int ntl = 0; ntl < 8; ++ntl)
#pragma unroll
        for (int q = 0; q < 3; ++q)
            Blds[((w * 8 + ntl) * 3 + q) * 64 + lane] = bw[(ntl * 16 + 12 + q) * 64];

    for (int t = tid; t < 16 * 520; t += 256) ((_Float16*)hA[0])[t] = (_Float16)0.f;
    __syncthreads();

    const int mr   = (lane >> 4) << 2;          // C rows (batch offset base)
    const int ncol = w * 128 + (lane & 15);     // C col base
    for (int s = 0; s < S_LEN; ++s) {
        const int par = s & 1;
        float* xs = xp + (size_t)s * BH + (size_t)(g * 16 + mr) * HID + ncol;
        // xp prefetch — independent, consumed after the MFMA phase
        float xpv[8][4];
#pragma unroll
        for (int ntl = 0; ntl < 8; ++ntl)
#pragma unroll
            for (int r = 0; r < 4; ++r)
                xpv[ntl][r] = xs[(size_t)r * HID + ntl * 16];
        // streamed kt=15 B-frags (32 KB/CU total -> L1-resident)
        f16x8 sw[8];
#pragma unroll
        for (int ntl = 0; ntl < 8; ++ntl)
            sw[ntl] = __builtin_bit_cast(f16x8, bw[(ntl * 16 + 15) * 64]);

        f32x4 acc[8] = {};
#pragma unroll
        for (int kt = 0; kt < 16; ++kt) {
            f16x8 aF = *(const f16x8*)&hA[par][lane & 15][kt * 32 + (lane >> 4) * 8];
#pragma unroll
            for (int ntl = 0; ntl < 8; ++ntl) {
                f16x8 bF = (kt < 12)
                             ? Breg[ntl * 12 + kt]
                             : (kt < 15)
                                 ? __builtin_bit_cast(f16x8,
                                       Blds[((w * 8 + ntl) * 3 + (kt - 12)) * 64 + lane])
                                 : sw[ntl];
                acc[ntl] = __builtin_amdgcn_mfma_f32_16x16x32_f16(aF, bF, acc[ntl], 0, 0, 0);
            }
        }
        // epilogue: add xp, tanh, write hidden_seq (in place) + next h state
#pragma unroll
        for (int ntl = 0; ntl < 8; ++ntl)
#pragma unroll
            for (int r = 0; r < 4; ++r) {
                float v = tanhf(acc[ntl][r] + xpv[ntl][r]);
                xs[(size_t)r * HID + ntl * 16] = v;
                hA[par ^ 1][mr + r][ncol + ntl * 16] = (_Float16)v;
            }
        asm volatile("s_waitcnt lgkmcnt(0)" ::: "memory");
        asm volatile("s_barrier" ::: "memory");
    }
}

// scores: sc_g[b][s] = dot(hbuf[s][b][:], hbuf[S-1][b][:]). Grid (64, 8), 256 thr.
__global__ __launch_bounds__(256) void attn_sc(const float* __restrict__ hbuf,
                                               float* __restrict__ sc_g) {
    const int b     = blockIdx.x;
    const int chunk = blockIdx.y;
    const int tid   = threadIdx.x;
    const int lane  = tid & 63;
    const int wv    = tid >> 6;
    __shared__ float fh[HID];
    fh[tid] = hbuf[(size_t)(S_LEN - 1) * BH + (size_t)b * HID + tid];
    fh[tid + 256] = hbuf[(size_t)(S_LEN - 1) * BH + (size_t)b * HID + tid + 256];
    __syncthreads();
    float4 f0 = *(const float4*)&fh[lane * 8];
    float4 f1 = *(const float4*)&fh[lane * 8 + 4];
    for (int i = 0; i < 32; ++i) {
        int s = chunk * 128 + wv * 32 + i;
        const float* hr = hbuf + (size_t)s * BH + (size_t)b * HID + lane * 8;
        float4 a0 = *(const float4*)hr;
        float4 a1 = *(const float4*)(hr + 4);
        float p = a0.x * f0.x + a0.y * f0.y + a0.z * f0.z + a0.w * f0.w +
                  a1.x * f1.x + a1.y * f1.y + a1.z * f1.z + a1.w * f1.w;
#pragma unroll
        for (int off = 32; off; off >>= 1) p += __shfl_down(p, off, 64);
        if (lane == 0) sc_g[(size_t)b * S_LEN + s] = p;
    }
}

// softmax (redundant per h-chunk) + context. Grid (64, 4), 256 thr, 128 h/WG.
__global__ __launch_bounds__(256) void attn_ctx(const float* __restrict__ hbuf,
                                                const float* __restrict__ sc_g,
                                                float* __restrict__ ctx_g) {
    const int b   = blockIdx.x;
    const int hc  = blockIdx.y * 128;
    const int tid = threadIdx.x;
    const int lane = tid & 63;
    const int wv   = tid >> 6;
    __shared__ float sc[S_LEN];
    __shared__ float red[4];
    __shared__ float part[256];
    for (int i = tid; i < S_LEN; i += 256) sc[i] = sc_g[(size_t)b * S_LEN + i];
    __syncthreads();
    float m = -1e30f;
    for (int i = tid; i < S_LEN; i += 256) m = fmaxf(m, sc[i]);
#pragma unroll
    for (int off = 32; off; off >>= 1) m = fmaxf(m, __shfl_down(m, off, 64));
    if (lane == 0) red[wv] = m;
    __syncthreads();
    m = fmaxf(fmaxf(red[0], red[1]), fmaxf(red[2], red[3]));
    float sum = 0.f;
    for (int i = tid; i < S_LEN; i += 256) {
        float e = __expf(sc[i] - m);
        sc[i] = e;
        sum += e;
    }
#pragma unroll
    for (int off = 32; off; off >>= 1) sum += __shfl_down(sum, off, 64);
    __syncthreads();
    if (lane == 0) red[wv] = sum;
    __syncthreads();
    float inv = 1.f / (red[0] + red[1] + red[2] + red[3]);
    const int h  = hc + (tid & 127);
    const int sh = tid >> 7;
    const float* hp = hbuf + (size_t)sh * 512 * BH + (size_t)b * HID + h;
    float c = 0.f;
#pragma unroll 4
    for (int s2 = 0; s2 < 512; ++s2)
        c += sc[sh * 512 + s2] * hp[(size_t)s2 * BH];
    part[tid] = c;
    __syncthreads();
    if (tid < 128) ctx_g[(size_t)b * HID + hc + tid] = (part[tid] + part[tid + 128]) * inv;
}

// out[b][o] = b_ho[o] + dot(ctx_g[b][:], W_ho[o][:]). Grid 64, 256 thr.
__global__ __launch_bounds__(256) void attn_fin(const float* __restrict__ ctx_g,
                                                const float* __restrict__ W_ho,
                                                const float* __restrict__ b_ho,
                                                float* __restrict__ out) {
    const int b   = blockIdx.x;
    const int tid = threadIdx.x;
    __shared__ float ctx[HID];
    ctx[tid] = ctx_g[(size_t)b * HID + tid];
    ctx[tid + 256] = ctx_g[(size_t)b * HID + tid + 256];
    __syncthreads();
    float o = b_ho[tid];
    const float* wr = W_ho + (size_t)tid * HID;
#pragma unroll 4
    for (int k = 0; k < HID; ++k) o += wr[k] * ctx[k];
    out[(size_t)b * OUT_SZ + tid] = o;
}

extern "C" void kernel_launch(void* const* d_in, const int* in_sizes, int n_in,
                              void* d_out, int out_size, void* d_ws, size_t ws_size,
                              hipStream_t stream) {
    const float* x    = (const float*)d_in[0];
    const float* W_ih = (const float*)d_in[1];
    const float* b_ih = (const float*)d_in[2];
    const float* W_ho = (const float*)d_in[3];
    const float* b_ho = (const float*)d_in[4];
    float* out = (float*)d_out;
    float* ws  = (float*)d_ws;

    float* xp = ws;
    unsigned int* wbase = (unsigned int*)(ws + XP_FLOATS);
    uint4* whB   = (uint4*)wbase;                 // 32768 uint4 = 512 KB
    uint4* wpk   = (uint4*)(wbase + 131072);      // 16384 uint4 = 256 KB
    float* sc_g  = (float*)wbase;                 // overlay, post-rnn
    float* ctx_g = (float*)(wbase + 65536);       // overlay, post-rnn

    pack_whB<<<dim3(128), dim3(256), 0, stream>>>(W_ih, whB);
    pack_wf16<<<dim3(64), dim3(256), 0, stream>>>(W_ih, wpk);
    xproj_mfma<<<dim3(1024, 2), dim3(256), 0, stream>>>(x, wpk, b_ih, xp);
    rnn_mfma<<<dim3(4), dim3(256), 0, stream>>>(whB, xp);
    attn_sc<<<dim3(64, 8), dim3(256), 0, stream>>>(xp, sc_g);
    attn_ctx<<<dim3(64, 4), dim3(256), 0, stream>>>(xp, sc_g, ctx_g);
    attn_fin<<<dim3(64), dim3(256), 0, stream>>>(ctx_g, W_ho, b_ho, out);
}